// Round 6
// baseline (1568.717 us; speedup 1.0000x reference)
//
#include <hip/hip_runtime.h>
#include <hip/hip_bf16.h>
#include <math.h>

#define H_ 8
#define K_ 128
#define C_ 64
#define D_ 1024
#define T_ 4096
#define B_ 4
#define N_CH 64           // T_/C_
#define BT_ (B_*T_)

typedef __attribute__((ext_vector_type(8))) short bf16x8;
typedef __attribute__((ext_vector_type(4))) float f32x4;
typedef __hip_bfloat16 bf16;

__device__ __forceinline__ float siluf(float x){ return x / (1.0f + expf(-x)); }
// exp with argument clamped to <=0 (valid data always has arg<=0; NaN arg -> fminf gives 0)
__device__ __forceinline__ float expn(float x){ return expf(fminf(x, 0.f)); }
// flush NaN/inf to 0 (no-op for valid data)
__device__ __forceinline__ float sanf(float v){ return (__builtin_fabsf(v) <= 1e30f) ? v : 0.f; }

__device__ __forceinline__ void ld_bf8(const bf16* p, float* o){
  uint4 u = *(const uint4*)p;
  o[0]=__uint_as_float(u.x<<16); o[1]=__uint_as_float(u.x&0xffff0000u);
  o[2]=__uint_as_float(u.y<<16); o[3]=__uint_as_float(u.y&0xffff0000u);
  o[4]=__uint_as_float(u.z<<16); o[5]=__uint_as_float(u.z&0xffff0000u);
  o[6]=__uint_as_float(u.w<<16); o[7]=__uint_as_float(u.w&0xffff0000u);
}
__device__ __forceinline__ void ld_bf8s(const bf16* p, float* o){
  ld_bf8(p, o);
#pragma unroll
  for (int e=0;e<8;e++) o[e] = sanf(o[e]);
}
__device__ __forceinline__ void ld_bf4(const bf16* p, float* o){
  uint2 u = *(const uint2*)p;
  o[0]=__uint_as_float(u.x<<16); o[1]=__uint_as_float(u.x&0xffff0000u);
  o[2]=__uint_as_float(u.y<<16); o[3]=__uint_as_float(u.y&0xffff0000u);
}
__device__ __forceinline__ void ld_bf4s(const bf16* p, float* o){
  ld_bf4(p, o);
#pragma unroll
  for (int e=0;e<4;e++) o[e] = sanf(o[e]);
}
__device__ __forceinline__ unsigned short f2bfu(float f){
  bf16 h = __float2bfloat16(f);
  return *reinterpret_cast<unsigned short*>(&h);
}
__device__ __forceinline__ uint2 pack_bf4(const float* v){
  uint2 r;
  r.x = (unsigned)f2bfu(v[0]) | ((unsigned)f2bfu(v[1])<<16);
  r.y = (unsigned)f2bfu(v[2]) | ((unsigned)f2bfu(v[3])<<16);
  return r;
}

// ---------------- fp32 -> bf16 cast ----------------
__global__ __launch_bounds__(256) void cast_f2b(
    const float* __restrict__ src, bf16* __restrict__ dst, int n4)
{
  int i = blockIdx.x*256 + threadIdx.x;
  if (i >= n4) return;
  float4 v = *(const float4*)&src[(size_t)i*4];
  float a[4] = {v.x, v.y, v.z, v.w};
  *(uint2*)&dst[(size_t)i*4] = pack_bf4(a);
}

// ---------------- MFMA GEMM: Y[M,N] = X[M,K](bf16) @ W[N,K](bf16)^T, OUT_T output ----------------
template<typename OUT_T>
__global__ __launch_bounds__(256) void gemm_bt_mfma(
    const bf16* __restrict__ X, const bf16* __restrict__ W,
    OUT_T* __restrict__ Y, int M, int N, int K)
{
  __shared__ __align__(16) bf16 As[128][72];
  __shared__ __align__(16) bf16 Bs[128][72];
  const int tid = threadIdx.x;
  const int wv = tid >> 6;
  const int lane = tid & 63;
  const int row0 = blockIdx.y*128, col0 = blockIdx.x*128;
  const int mw = (wv&1)*64, nw = (wv>>1)*64;
  const int q = lane >> 4;
  const int l15 = lane & 15;
  f32x4 acc[4][4];
#pragma unroll
  for (int mi=0;mi<4;mi++)
#pragma unroll
    for (int ni=0;ni<4;ni++) acc[mi][ni] = (f32x4){0.f,0.f,0.f,0.f};

  const int lr = tid >> 3;          // 0..31
  const int lc = (tid & 7) * 8;     // 0..56
  for (int k0=0;k0<K;k0+=64){
#pragma unroll
    for (int i=0;i<4;i++){
      int r = lr + i*32;
      *(uint4*)&As[r][lc] = *(const uint4*)&X[(size_t)(row0+r)*K + k0 + lc];
      *(uint4*)&Bs[r][lc] = *(const uint4*)&W[(size_t)(col0+r)*K + k0 + lc];
    }
    __syncthreads();
#pragma unroll
    for (int ks=0; ks<64; ks+=32){
      bf16x8 af[4], bfr[4];
#pragma unroll
      for (int i=0;i<4;i++){
        af[i]  = *(const bf16x8*)&As[mw + i*16 + l15][ks + q*8];
        bfr[i] = *(const bf16x8*)&Bs[nw + i*16 + l15][ks + q*8];
      }
#pragma unroll
      for (int mi=0;mi<4;mi++)
#pragma unroll
        for (int ni=0;ni<4;ni++)
          acc[mi][ni] = __builtin_amdgcn_mfma_f32_16x16x32_bf16(af[mi], bfr[ni], acc[mi][ni], 0,0,0);
    }
    __syncthreads();
  }
#pragma unroll
  for (int mi=0;mi<4;mi++){
#pragma unroll
    for (int reg=0;reg<4;reg++){
      int row = row0 + mw + mi*16 + q*4 + reg;
#pragma unroll
      for (int ni=0;ni<4;ni++){
        int col = col0 + nw + ni*16 + l15;
        if constexpr (sizeof(OUT_T) == 2)
          Y[(size_t)row*N + col] = (OUT_T)__float2bfloat16(acc[mi][ni][reg]);
        else
          Y[(size_t)row*N + col] = (OUT_T)acc[mi][ni][reg];
      }
    }
  }
}

// ------------- beta = sigmoid(x@Wb^T), decay = -exp(A_log)*softplus(x@Wa^T+dt_bias) -------------
__global__ __launch_bounds__(256) void proj_small(
    const float* __restrict__ x, const float* __restrict__ Wb, const float* __restrict__ Wa,
    const float* __restrict__ dt_bias, const float* __restrict__ A_log,
    float* __restrict__ beta_out, float* __restrict__ dec_out)
{
  const int w = threadIdx.x >> 6;
  const int lane = threadIdx.x & 63;
  const int bt = blockIdx.x*4 + w;
  const int b = bt >> 12, t = bt & (T_-1);
  const float* xr = x + (size_t)bt*D_;
  float xv[16];
#pragma unroll
  for (int p=0;p<4;p++){
    float4 v = *(const float4*)&xr[lane*16 + p*4];
    xv[p*4+0]=v.x; xv[p*4+1]=v.y; xv[p*4+2]=v.z; xv[p*4+3]=v.w;
  }
  float accb[H_], acca[H_];
#pragma unroll
  for (int h=0;h<H_;h++){
    float sb=0.f, sa=0.f;
#pragma unroll
    for (int p=0;p<4;p++){
      float4 wb = *(const float4*)&Wb[(size_t)h*D_ + lane*16 + p*4];
      float4 wa = *(const float4*)&Wa[(size_t)h*D_ + lane*16 + p*4];
      sb += xv[p*4+0]*wb.x + xv[p*4+1]*wb.y + xv[p*4+2]*wb.z + xv[p*4+3]*wb.w;
      sa += xv[p*4+0]*wa.x + xv[p*4+1]*wa.y + xv[p*4+2]*wa.z + xv[p*4+3]*wa.w;
    }
    accb[h]=sb; acca[h]=sa;
  }
#pragma unroll
  for (int h=0;h<H_;h++){
#pragma unroll
    for (int m=1;m<64;m<<=1){
      accb[h] += __shfl_xor(accb[h], m, 64);
      acca[h] += __shfl_xor(acca[h], m, 64);
    }
  }
  if (lane < H_) {
    int h = lane;
    beta_out[(size_t)(b*H_+h)*T_ + t] = 1.f/(1.f+expf(-accb[h]));
  } else if (lane < 2*H_) {
    int h = lane - H_;
    float z = acca[h] + dt_bias[h];
    float sp = fmaxf(z,0.f) + log1pf(expf(-fabsf(z)));
    dec_out[(size_t)(b*H_+h)*T_ + t] = -expf(A_log[h]) * sp;
  }
}

// ------------- xinv[b,h,t] = rsqrt(sum_k x[b,t,h,k]^2 + 1e-6) -------------
__global__ __launch_bounds__(256) void xinv_kernel(
    const float* __restrict__ x, float* __restrict__ xinv)
{
  const int bt = blockIdx.x;
  const int b = bt >> 12, t = bt & (T_-1);
  const int tid = threadIdx.x;
  float4 xv = *(const float4*)&x[(size_t)bt*D_ + tid*4];
  float ss = xv.x*xv.x + xv.y*xv.y + xv.z*xv.z + xv.w*xv.w;
#pragma unroll
  for (int m=1;m<32;m<<=1) ss += __shfl_xor(ss, m, 32);
  const int h = tid >> 5;
  if ((tid & 31) == 0)
    xinv[(size_t)(b*H_+h)*T_ + t] = rsqrtf(ss + 1e-6f);
}

// ------------- per-chunk cumsum of decay (fp32) -------------
__global__ __launch_bounds__(256) void cumsum_dec(
    const float* __restrict__ dec_raw, float* __restrict__ dec_cum)
{
  int g = blockIdx.x*4 + (threadIdx.x>>6);
  int lane = threadIdx.x & 63;
  float v = sanf(dec_raw[(size_t)g*C_ + lane]);
#pragma unroll
  for (int off=1; off<64; off<<=1){
    float u = __shfl_up(v, off, 64);
    if (lane >= off) v += u;
  }
  dec_cum[(size_t)g*C_ + lane] = v;
}

// ------------- per-chunk: A, attn, conv+silu fused RHS, forward substitution -------------
__global__ __launch_bounds__(256) void chunk_prep(
    const bf16* __restrict__ xb, const float* __restrict__ xinv,
    const bf16* __restrict__ vpre, const float* __restrict__ cw, const float* __restrict__ cb,
    const float* __restrict__ beta, const float* __restrict__ dec,
    bf16* __restrict__ vchk, bf16* __restrict__ wkc, bf16* __restrict__ attn)
{
  __shared__ float s_m[C_][132];
  __shared__ float s_a[C_][66];
  __shared__ float s_r[16][132];
  __shared__ float s_cw[K_][4];
  __shared__ float s_cb[K_];
  __shared__ float s_beta[C_], s_dec[C_];
  const int tid = threadIdx.x;
  const int chunk = blockIdx.x;
  const int bh = chunk >> 6;
  const int nc = chunk & 63;
  const int b = bh >> 3, h = bh & 7;
  const int t0 = nc * C_;
  const size_t xrow = (size_t)b*T_;
  const size_t kobase = ((size_t)bh*T_ + t0) * K_;
  const int c_ld = tid >> 2;
  const int kb_ld = (tid & 3) * 32;

  // stage wk rows (shifted, l2-normalized x) into s_m
  {
    int tm1 = t0 + c_ld - 1;
    float inv = (tm1 >= 0) ? sanf(xinv[(size_t)bh*T_ + tm1]) : 0.f;
    int tr = tm1 < 0 ? 0 : tm1;
    const bf16* s = xb + (xrow + tr)*D_ + h*K_ + kb_ld;
#pragma unroll
    for (int i=0;i<4;i++){
      float v[8]; ld_bf8(s + i*8, v);
#pragma unroll
      for (int e=0;e<8;e++) s_m[c_ld][kb_ld + i*8 + e] = v[e]*inv;
    }
  }
  if (tid < K_){
#pragma unroll
    for (int j=0;j<4;j++) s_cw[tid][j] = cw[(h*K_+tid)*4 + j];
    s_cb[tid] = cb[h*K_+tid];
  }
  if (tid < C_){
    s_beta[tid] = sanf(beta[(size_t)bh*T_ + t0 + tid]);
    s_dec[tid]  = sanf(dec [(size_t)bh*T_ + t0 + tid]);
  }
  __syncthreads();

  // A[i][j] = -beta[i]*(wk[i].wk[j])*exp(dec[i]-dec[j]), i>j
  {
    const int i = tid >> 2;
    const int jb = (tid & 3) * 16;
    const float bi = s_beta[i], di = s_dec[i];
    for (int jj=0;jj<16;jj++){
      int j = jb + jj;
      if (j < i){
        float dot = 0.f;
#pragma unroll 8
        for (int k=0;k<K_;k++) dot += s_m[i][k]*s_m[j][k];
        s_a[i][j] = -bi * expn(di - s_dec[j]) * dot;
      }
    }
  }
  __syncthreads();

  // attn = tril(rk @ wk^T * L), dense bf16; rk rows staged from x*xinv*rsqrtK
  for (int p=0;p<4;p++){
    {
      int lcx = tid >> 4;
      int kb2 = (tid & 15)*8;
      int tr = t0 + p*16 + lcx;
      float sc = sanf(xinv[(size_t)bh*T_ + tr]) * 0.08838834764831845f;
      float v[8]; ld_bf8(xb + (xrow + tr)*D_ + h*K_ + kb2, v);
#pragma unroll
      for (int e=0;e<8;e++) s_r[lcx][kb2+e] = v[e]*sc;
    }
    __syncthreads();
    {
      int lcx = tid >> 4;
      int c = p*16 + lcx;
      float dc = s_dec[c];
      int dbase = tid & 15;
#pragma unroll
      for (int qq=0;qq<4;qq++){
        int d = dbase + qq*16;
        float val = 0.f;
        if (d <= c){
          float dot=0.f;
#pragma unroll 8
          for (int k=0;k<K_;k++) dot += s_r[lcx][k]*s_m[d][k];
          val = dot * expn(dc - s_dec[d]);
        }
        attn[(size_t)chunk*4096 + c*64 + d] = __float2bfloat16(val);
      }
    }
    __syncthreads();
  }

  // Solve 1 RHS: silu(depthwise_conv(vpre)) * beta
  {
    int t = t0 + c_ld;
    float acc[32];
#pragma unroll
    for (int e=0;e<32;e++) acc[e] = s_cb[kb_ld+e];
#pragma unroll
    for (int j=0;j<4;j++){
      int ts = t + j - 3;
      if (ts >= 0){
        const bf16* s = vpre + (xrow + ts)*D_ + h*K_ + kb_ld;
#pragma unroll
        for (int i=0;i<4;i++){
          float v[8]; ld_bf8s(s + i*8, v);
#pragma unroll
          for (int e=0;e<8;e++) acc[i*8+e] += v[e]*s_cw[kb_ld+i*8+e][j];
        }
      }
    }
    float bc = s_beta[c_ld];
#pragma unroll
    for (int e=0;e<32;e++) s_m[c_ld][kb_ld+e] = siluf(acc[e])*bc;
  }
  __syncthreads();
  for (int i=1;i<C_;i++){
    if (tid < K_){
      float u = s_m[i][tid];
      for (int j=0;j<i;j++) u += s_a[i][j]*s_m[j][tid];
      s_m[i][tid] = u;
    }
    __syncthreads();
  }
  {
    bf16* d = vchk + kobase + (size_t)c_ld*K_ + kb_ld;
#pragma unroll
    for (int i=0;i<8;i++) *(uint2*)&d[i*4] = pack_bf4(&s_m[c_ld][kb_ld + i*4]);
  }
  __syncthreads();

  // Solve 2 RHS: wk * beta * exp(dec)
  {
    int tm1 = t0 + c_ld - 1;
    float inv = (tm1 >= 0) ? sanf(xinv[(size_t)bh*T_ + tm1]) : 0.f;
    int tr = tm1 < 0 ? 0 : tm1;
    float sc = inv * s_beta[c_ld] * expn(s_dec[c_ld]);
    const bf16* s = xb + (xrow + tr)*D_ + h*K_ + kb_ld;
#pragma unroll
    for (int i=0;i<4;i++){
      float v[8]; ld_bf8(s + i*8, v);
#pragma unroll
      for (int e=0;e<8;e++) s_m[c_ld][kb_ld + i*8 + e] = v[e]*sc;
    }
  }
  __syncthreads();
  for (int i=1;i<C_;i++){
    if (tid < K_){
      float u = s_m[i][tid];
      for (int j=0;j<i;j++) u += s_a[i][j]*s_m[j][tid];
      s_m[i][tid] = u;
    }
    __syncthreads();
  }
  {
    bf16* d = wkc + kobase + (size_t)c_ld*K_ + kb_ld;
#pragma unroll
    for (int i=0;i<8;i++) *(uint2*)&d[i*4] = pack_bf4(&s_m[c_ld][kb_ld + i*4]);
  }
}

// ------------- sequential chunk scan; vo holds vchk on entry, o on exit (same buffer) -------------
__global__ __launch_bounds__(256) void scan_kernel(
    const bf16* __restrict__ xb, const float* __restrict__ xinv,
    bf16* vo, const bf16* __restrict__ wkc,
    const bf16* __restrict__ attn, const float* __restrict__ dec)
{
  __shared__ float s_m[C_][132];     // staging: wkc / rk / attn / wk
  __shared__ float s_S[K_][20];      // state slice 128x16 (fp32)
  __shared__ float s_vn[C_][20];
  __shared__ float s_dec[C_], s_dw[C_], s_ed[C_];
  float* s_att = &s_m[0][0];         // aliased, stride 68

  const int tid = threadIdx.x;
  const int bh = blockIdx.x >> 3;
  const int b = bh >> 3, h = bh & 7;
  const int g  = blockIdx.x & 7;
  const int j0 = g*16;
  const int jq = (tid & 3)*4;
  const int cq = tid >> 2;
  const int kb_ld = (tid & 3)*32;
  const size_t xrow = (size_t)b*T_;

  for (int e = tid; e < K_*20; e += 256) (&s_S[0][0])[e] = 0.f;
  __syncthreads();

  for (int nc=0; nc<N_CH; nc++){
    const int t0 = nc*C_;
    const size_t rowb = (size_t)bh*T_ + t0;
    if (tid < C_){
      float dv = sanf(dec[rowb + tid]);
      s_dec[tid] = dv;
      s_ed[tid] = expn(dv);
    }
    // stage wkc
    {
      const bf16* s = wkc + rowb*K_ + (size_t)cq*K_ + kb_ld;
#pragma unroll
      for (int i=0;i<4;i++){
        float v[8]; ld_bf8s(s + i*8, v);
#pragma unroll
        for (int e=0;e<8;e++) s_m[cq][kb_ld + i*8 + e] = v[e];
      }
    }
    __syncthreads();
    if (tid < C_) s_dw[tid] = expn(s_dec[C_-1] - s_dec[tid]);

    // step 1: v_new = v - wkc @ S
    {
      float acc[4];
      ld_bf4s(vo + (rowb + cq)*K_ + j0 + jq, acc);
#pragma unroll 8
      for (int k=0;k<K_;k++){
        float a = s_m[cq][k];
        acc[0] -= a*s_S[k][jq+0]; acc[1] -= a*s_S[k][jq+1];
        acc[2] -= a*s_S[k][jq+2]; acc[3] -= a*s_S[k][jq+3];
      }
      *(float4*)&s_vn[cq][jq] = make_float4(acc[0],acc[1],acc[2],acc[3]);
    }
    __syncthreads();
    // stage rk = x[t]*xinv[t]*rsqrtK
    {
      int t = t0 + cq;
      float sc = sanf(xinv[(size_t)bh*T_ + t]) * 0.08838834764831845f;
      const bf16* s = xb + (xrow + t)*D_ + h*K_ + kb_ld;
#pragma unroll
      for (int i=0;i<4;i++){
        float v[8]; ld_bf8(s + i*8, v);
#pragma unroll
        for (int e=0;e<8;e++) s_m[cq][kb_ld + i*8 + e] = v[e]*sc;
      }
    }
    __syncthreads();
    // step 2a: o_inter = (rk * exp(dec)) @ S
    float oacc[4] = {0.f,0.f,0.f,0.f};
    {
#pragma unroll 8
      for (int k=0;k<K_;k++){
        float a = s_m[cq][k];
        oacc[0] += a*s_S[k][jq+0]; oacc[1] += a*s_S[k][jq+1];
        oacc[2] += a*s_S[k][jq+2]; oacc[3] += a*s_S[k][jq+3];
      }
      float ec = s_ed[cq];
      oacc[0]*=ec; oacc[1]*=ec; oacc[2]*=ec; oacc[3]*=ec;
    }
    __syncthreads();
    // stage attn (64x64 bf16 -> fp32, stride 68)
    {
      const bf16* ab = attn + (size_t)(bh*N_CH + nc)*4096;
#pragma unroll
      for (int r=0;r<2;r++){
        int e = tid*8 + r*2048;
        int c = e >> 6, d = e & 63;
        float v[8]; ld_bf8s(ab + e, v);
#pragma unroll
        for (int q2=0;q2<8;q2++) s_att[c*68 + d + q2] = v[q2];
      }
    }
    __syncthreads();
    // step 2b: o += attn @ v_new ; write o (same buffer as vchk, same rows/cols)
    {
#pragma unroll 8
      for (int d=0; d<C_; d++){
        float a = s_att[cq*68 + d];
        oacc[0] += a*s_vn[d][jq+0]; oacc[1] += a*s_vn[d][jq+1];
        oacc[2] += a*s_vn[d][jq+2]; oacc[3] += a*s_vn[d][jq+3];
      }
      *(uint2*)&vo[(rowb + cq)*K_ + j0 + jq] = pack_bf4(oacc);
    }
    __syncthreads();
    // stage wk = x[t-1]*xinv[t-1] (shifted)
    {
      int tm1 = t0 + cq - 1;
      float inv = (tm1 >= 0) ? sanf(xinv[(size_t)bh*T_ + tm1]) : 0.f;
      int tr = tm1 < 0 ? 0 : tm1;
      const bf16* s = xb + (xrow + tr)*D_ + h*K_ + kb_ld;
#pragma unroll
      for (int i=0;i<4;i++){
        float v[8]; ld_bf8(s + i*8, v);
#pragma unroll
        for (int e=0;e<8;e++) s_m[cq][kb_ld + i*8 + e] = v[e]*inv;
      }
    }
    __syncthreads();
    // step 3: S = S*exp(dec[63]) + (wk*dw)^T @ v_new
    {
      float sc = expn(s_dec[C_-1]);
#pragma unroll
      for (int p=0;p<2;p++){
        int k = cq + p*64;
        float sacc[4];
        sacc[0]=s_S[k][jq+0]*sc; sacc[1]=s_S[k][jq+1]*sc;
        sacc[2]=s_S[k][jq+2]*sc; sacc[3]=s_S[k][jq+3]*sc;
#pragma unroll 8
        for (int c=0;c<C_;c++){
          float wv = s_m[c][k] * s_dw[c];
          sacc[0] += wv*s_vn[c][jq+0]; sacc[1] += wv*s_vn[c][jq+1];
          sacc[2] += wv*s_vn[c][jq+2]; sacc[3] += wv*s_vn[c][jq+3];
        }
        *(float4*)&s_S[k][jq] = make_float4(sacc[0],sacc[1],sacc[2],sacc[3]);
      }
    }
    __syncthreads();
  }
}

// ------------- per-head RMSNorm * norm_w * silu(gate); gate buffer overwritten in place -------------
__global__ __launch_bounds__(256) void norm_gate(
    const bf16* __restrict__ o, bf16* gio, const float* __restrict__ norm_w)
{
  const int bt = blockIdx.x;
  const int b = bt >> 12, t = bt & (T_-1);
  const int tid = threadIdx.x;
  const int h = tid >> 5;
  const int kk = (tid & 31)*4;
  float ov[4];
  ld_bf4s(o + ((size_t)(b*H_+h)*T_ + t)*K_ + kk, ov);
  float ss = ov[0]*ov[0] + ov[1]*ov[1] + ov[2]*ov[2] + ov[3]*ov[3];
#pragma unroll
  for (int m=1;m<32;m<<=1) ss += __shfl_xor(ss, m, 32);
  float r = rsqrtf(ss*(1.f/128.f) + 1e-5f);
  float4 nw = *(const float4*)&norm_w[kk];
  float gv[4];
  ld_bf4s(gio + (size_t)bt*D_ + tid*4, gv);
  float res[4];
  res[0] = ov[0]*r*nw.x * siluf(gv[0]);
  res[1] = ov[1]*r*nw.y * siluf(gv[1]);
  res[2] = ov[2]*r*nw.z * siluf(gv[2]);
  res[3] = ov[3]*r*nw.w * siluf(gv[3]);
  *(uint2*)&gio[(size_t)bt*D_ + tid*4] = pack_bf4(res);
}

extern "C" void kernel_launch(void* const* d_in, const int* in_sizes, int n_in,
                              void* d_out, int out_size, void* d_ws, size_t ws_size,
                              hipStream_t stream)
{
  const float* x       = (const float*)d_in[0];
  const float* Wv      = (const float*)d_in[1];
  const float* Wg      = (const float*)d_in[2];
  const float* Wo      = (const float*)d_in[3];
  const float* Wb      = (const float*)d_in[4];
  const float* Wa      = (const float*)d_in[5];
  const float* dt_bias = (const float*)d_in[6];
  const float* A_log   = (const float*)d_in[7];
  const float* norm_w  = (const float*)d_in[8];
  const float* conv_w  = (const float*)d_in[9];
  const float* conv_b  = (const float*)d_in[10];
  float* out = (float*)d_out;

  const size_t BTD = (size_t)B_*T_*D_;
  const size_t BHT = (size_t)B_*H_*T_;
  const size_t DD  = (size_t)D_*D_;

  // ws layout (~108.6 MB): fp32 smalls, bf16 weight copies, then big bf16 buffers
  float* beta = (float*)d_ws;          // 0.5 MiB each
  float* decr = beta + BHT;
  float* decc = decr + BHT;
  float* xinv = decc + BHT;
  bf16* Wvb = (bf16*)(xinv + BHT);     // 2 MiB each
  bf16* Wgb = Wvb + DD;
  bf16* Wob = Wgb + DD;
  bf16* xb   = Wob + DD;               // 33.5 MiB: bf16 copy of x
  bf16* vpre = xb + BTD;               // 33.5 MiB: Wv-GEMM out; later Wg-GEMM out / og
  bf16* wkc  = vpre + BTD;             // 33.5 MiB
  // d_out (67 MB fp32) hosts: [vchk->o bf16: BTD][attn bf16: BTD/2]
  bf16* vo   = (bf16*)d_out;
  bf16* attn = vo + BTD;

  dim3 gemm_grid(D_/128, BT_/128);   // (8, 128)
  cast_f2b<<<(BTD/4+255)/256, 256, 0, stream>>>(x, xb, BTD/4);
  cast_f2b<<<(DD/4+255)/256, 256, 0, stream>>>(Wv, Wvb, DD/4);
  cast_f2b<<<(DD/4+255)/256, 256, 0, stream>>>(Wg, Wgb, DD/4);
  cast_f2b<<<(DD/4+255)/256, 256, 0, stream>>>(Wo, Wob, DD/4);
  gemm_bt_mfma<bf16><<<gemm_grid, 256, 0, stream>>>(xb, Wvb, vpre, BT_, D_, D_);
  proj_small<<<BT_/4, 256, 0, stream>>>(x, Wb, Wa, dt_bias, A_log, beta, decr);
  xinv_kernel<<<BT_, 256, 0, stream>>>(x, xinv);
  cumsum_dec<<<(BHT/C_)/4, 256, 0, stream>>>(decr, decc);
  chunk_prep<<<B_*H_*N_CH, 256, 0, stream>>>(xb, xinv, vpre, conv_w, conv_b,
                                             beta, decc, vo /*vchk*/, wkc, attn);
  scan_kernel<<<B_*H_*8, 256, 0, stream>>>(xb, xinv, vo, wkc, attn, decc);
  gemm_bt_mfma<bf16><<<gemm_grid, 256, 0, stream>>>(xb, Wgb, vpre, BT_, D_, D_); // gate
  norm_gate<<<BT_, 256, 0, stream>>>(vo /*o*/, vpre /*gate->og*/, norm_w);
  gemm_bt_mfma<float><<<gemm_grid, 256, 0, stream>>>(vpre, Wob, out, BT_, D_, D_);
}